// Round 4
// baseline (890.069 us; speedup 1.0000x reference)
//
#include <hip/hip_runtime.h>
#include <hip/hip_bf16.h>

#define N_NODES 50000
#define N_EDGES 800000
// HEADS=4, OUT_CH=64, F=256 hard-coded below. All tensors float32.

// ---------------- CSR build (dst-sorted incoming edge lists) ----------------
__global__ void deg_kernel(const int* __restrict__ dst, int* __restrict__ cnt, int E) {
    int i = blockIdx.x * blockDim.x + threadIdx.x;
    if (i < E) atomicAdd(&cnt[dst[i]], 1);
}

__global__ void scan_kernel(const int* __restrict__ cnt, int* __restrict__ row_ptr,
                            int* __restrict__ row_tmp, int n) {
    __shared__ int sdata[1024];
    __shared__ int carry_s;
    if (threadIdx.x == 0) carry_s = 0;
    __syncthreads();
    for (int base = 0; base < n; base += 1024) {
        int i = base + threadIdx.x;
        int v = (i < n) ? cnt[i] : 0;
        sdata[threadIdx.x] = v;
        __syncthreads();
        for (int off = 1; off < 1024; off <<= 1) {
            int t = (threadIdx.x >= off) ? sdata[threadIdx.x - off] : 0;
            __syncthreads();
            sdata[threadIdx.x] += t;
            __syncthreads();
        }
        int carry = carry_s;
        int excl = carry + sdata[threadIdx.x] - v;
        if (i < n) { row_ptr[i] = excl; row_tmp[i] = excl; }
        __syncthreads();
        if (threadIdx.x == 1023) carry_s = carry + sdata[1023];
        __syncthreads();
    }
    if (threadIdx.x == 0) row_ptr[n] = carry_s;
}

__global__ void scatter_kernel(const int* __restrict__ src, const int* __restrict__ dst,
                               int* __restrict__ row_tmp, int* __restrict__ sorted_src, int E) {
    int i = blockIdx.x * blockDim.x + threadIdx.x;
    if (i < E) {
        int p = atomicAdd(&row_tmp[dst[i]], 1);
        sorted_src[p] = src[i];
    }
}

// ---------------- GEMM: H[M,256] = A[M,256] @ W[256,256], f32 ----
__global__ __launch_bounds__(256) void gemm_kernel(const float* __restrict__ A,
                                                   const float* __restrict__ W,
                                                   float* __restrict__ H, int M) {
    const int BM = 64, BN = 64, BK = 16, K = 256, N = 256;
    __shared__ float As[BK][BM + 1];
    __shared__ float Bs[BK][BN + 1];
    int brow = blockIdx.x * BM;
    int bcol = blockIdx.y * BN;
    int tid = threadIdx.x;
    int tx = tid & 15, ty = tid >> 4;
    float acc[4][4] = {};
    for (int k0 = 0; k0 < K; k0 += BK) {
        #pragma unroll
        for (int u = 0; u < 4; u++) {
            int q = tid * 4 + u;           // 0..1023
            int r = q >> 4, kk = q & 15;   // 64 rows x 16 k
            int row = brow + r;
            As[kk][r] = (row < M) ? A[(size_t)row * K + k0 + kk] : 0.f;
        }
        #pragma unroll
        for (int u = 0; u < 4; u++) {
            int q = tid * 4 + u;
            int kk = q >> 6, c = q & 63;   // 16 k x 64 cols
            Bs[kk][c] = W[(size_t)(k0 + kk) * N + bcol + c];
        }
        __syncthreads();
        #pragma unroll
        for (int kk = 0; kk < BK; kk++) {
            float a[4], b[4];
            #pragma unroll
            for (int i = 0; i < 4; i++) a[i] = As[kk][ty * 4 + i];
            #pragma unroll
            for (int j = 0; j < 4; j++) b[j] = Bs[kk][tx * 4 + j];
            #pragma unroll
            for (int i = 0; i < 4; i++)
                #pragma unroll
                for (int j = 0; j < 4; j++)
                    acc[i][j] += a[i] * b[j];
        }
        __syncthreads();
    }
    #pragma unroll
    for (int i = 0; i < 4; i++) {
        int row = brow + ty * 4 + i;
        if (row < M) {
            #pragma unroll
            for (int j = 0; j < 4; j++)
                H[(size_t)row * N + bcol + tx * 4 + j] = acc[i][j];
        }
    }
}

// ---------------- attention logits: one wave per node ----------------
__global__ __launch_bounds__(256) void att_kernel(const float* __restrict__ H,
                                                  const float* __restrict__ att_s,
                                                  const float* __restrict__ att_d,
                                                  float* __restrict__ a_src,
                                                  float* __restrict__ a_dst, int N) {
    int wid = blockIdx.x * 4 + (threadIdx.x >> 6);
    int lane = threadIdx.x & 63;
    if (wid >= N) return;
    #pragma unroll
    for (int h = 0; h < 4; h++) {
        float v = H[(size_t)wid * 256 + h * 64 + lane];
        float ps = v * att_s[h * 64 + lane];
        float pd = v * att_d[h * 64 + lane];
        #pragma unroll
        for (int off = 32; off > 0; off >>= 1) {
            ps += __shfl_xor(ps, off, 64);
            pd += __shfl_xor(pd, off, 64);
        }
        if (lane == 0) { a_src[wid * 4 + h] = ps; a_dst[wid * 4 + h] = pd; }
    }
}

// ---------------- per-dst softmax + weighted gather, one wave per node ------
// out = ELU( (sum_j w_j * h[src_j]) / (sum_j w_j + 1e-16) + bias ),
// w_j = exp(lrelu(a_src[src_j]+a_dst[i]) - m),  self-loop included inline.
__global__ __launch_bounds__(256) void agg_kernel(const float* __restrict__ H,
                                                  const float* __restrict__ a_src,
                                                  const float* __restrict__ a_dst,
                                                  const int* __restrict__ row_ptr,
                                                  const int* __restrict__ sorted_src,
                                                  const float* __restrict__ bias,
                                                  float* __restrict__ out, int N) {
    int i = blockIdx.x * 4 + (threadIdx.x >> 6);
    int lane = threadIdx.x & 63;
    if (i >= N) return;
    float ad[4], asi[4], m[4];
    #pragma unroll
    for (int h = 0; h < 4; h++) { ad[h] = a_dst[i * 4 + h]; asi[h] = a_src[i * 4 + h]; }
    #pragma unroll
    for (int h = 0; h < 4; h++) {
        float e = asi[h] + ad[h];
        m[h] = (e >= 0.f) ? e : 0.2f * e;   // self-loop logit
    }
    int start = row_ptr[i], end = row_ptr[i + 1];
    // pass 1: max over incoming edges (lane-parallel)
    for (int j = start + lane; j < end; j += 64) {
        int s = sorted_src[j];
        float4 av = *reinterpret_cast<const float4*>(a_src + (size_t)s * 4);
        float e;
        e = av.x + ad[0]; e = (e >= 0.f) ? e : 0.2f * e; m[0] = fmaxf(m[0], e);
        e = av.y + ad[1]; e = (e >= 0.f) ? e : 0.2f * e; m[1] = fmaxf(m[1], e);
        e = av.z + ad[2]; e = (e >= 0.f) ? e : 0.2f * e; m[2] = fmaxf(m[2], e);
        e = av.w + ad[3]; e = (e >= 0.f) ? e : 0.2f * e; m[3] = fmaxf(m[3], e);
    }
    #pragma unroll
    for (int h = 0; h < 4; h++)
        #pragma unroll
        for (int off = 32; off > 0; off >>= 1)
            m[h] = fmaxf(m[h], __shfl_xor(m[h], off, 64));
    // pass 2: weighted accumulation, lane = channel, wave walks edges together
    float acc[4] = {0.f, 0.f, 0.f, 0.f}, den[4] = {0.f, 0.f, 0.f, 0.f};
    {   // self loop
        #pragma unroll
        for (int h = 0; h < 4; h++) {
            float e = asi[h] + ad[h]; e = (e >= 0.f) ? e : 0.2f * e;
            float w = __expf(e - m[h]);
            den[h] += w;
            acc[h] += w * H[(size_t)i * 256 + h * 64 + lane];
        }
    }
    for (int j = start; j < end; j++) {
        int s = sorted_src[j];
        float4 av = *reinterpret_cast<const float4*>(a_src + (size_t)s * 4);
        const float* hr = H + (size_t)s * 256 + lane;
        float e, w;
        e = av.x + ad[0]; e = (e >= 0.f) ? e : 0.2f * e; w = __expf(e - m[0]); den[0] += w; acc[0] += w * hr[0];
        e = av.y + ad[1]; e = (e >= 0.f) ? e : 0.2f * e; w = __expf(e - m[1]); den[1] += w; acc[1] += w * hr[64];
        e = av.z + ad[2]; e = (e >= 0.f) ? e : 0.2f * e; w = __expf(e - m[2]); den[2] += w; acc[2] += w * hr[128];
        e = av.w + ad[3]; e = (e >= 0.f) ? e : 0.2f * e; w = __expf(e - m[3]); den[3] += w; acc[3] += w * hr[192];
    }
    #pragma unroll
    for (int h = 0; h < 4; h++) {
        float v = acc[h] / (den[h] + 1e-16f) + bias[h * 64 + lane];
        v = (v > 0.f) ? v : expm1f(v);      // ELU
        out[(size_t)i * 256 + h * 64 + lane] = v;
    }
}

extern "C" void kernel_launch(void* const* d_in, const int* in_sizes, int n_in,
                              void* d_out, int out_size, void* d_ws, size_t ws_size,
                              hipStream_t stream) {
    const float* x      = (const float*)d_in[0];
    const int*   eidx   = (const int*)d_in[1];
    const float* W1     = (const float*)d_in[2];
    const float* att_s1 = (const float*)d_in[3];
    const float* att_d1 = (const float*)d_in[4];
    const float* b1     = (const float*)d_in[5];
    const float* W2     = (const float*)d_in[6];
    const float* att_s2 = (const float*)d_in[7];
    const float* att_d2 = (const float*)d_in[8];
    const float* b2     = (const float*)d_in[9];
    float* out = (float*)d_out;

    const int N = N_NODES, E = N_EDGES;
    char* ws = (char*)d_ws;
    size_t off = 0;
    auto alloc = [&](size_t bytes) -> void* {
        void* p = ws + off;
        off += (bytes + 255) & ~(size_t)255;
        return p;
    };
    // total ws: ~56.6 MB
    float* h       = (float*)alloc((size_t)N * 256 * sizeof(float));   // 51.2 MB
    float* a_src   = (float*)alloc((size_t)N * 4 * sizeof(float));
    float* a_dst   = (float*)alloc((size_t)N * 4 * sizeof(float));
    int*   cnt     = (int*)  alloc((size_t)N * sizeof(int));
    int*   row_ptr = (int*)  alloc((size_t)(N + 1) * sizeof(int));
    int*   row_tmp = (int*)  alloc((size_t)N * sizeof(int));
    int*   sorted  = (int*)  alloc((size_t)E * sizeof(int));
    float* x2      = out;   // layer-1 activations live in d_out (f32), overwritten by layer 2
    (void)ws_size; (void)in_sizes; (void)n_in; (void)out_size;

    const int* e_src = eidx;
    const int* e_dst = eidx + E;

    // CSR build (shared by both layers)
    hipMemsetAsync(cnt, 0, N * sizeof(int), stream);
    deg_kernel<<<(E + 255) / 256, 256, 0, stream>>>(e_dst, cnt, E);
    scan_kernel<<<1, 1024, 0, stream>>>(cnt, row_ptr, row_tmp, N);
    scatter_kernel<<<(E + 255) / 256, 256, 0, stream>>>(e_src, e_dst, row_tmp, sorted, E);

    dim3 ggrid((N + 63) / 64, 4);
    int nblk = (N + 3) / 4;
    // layer 1
    gemm_kernel<<<ggrid, 256, 0, stream>>>(x, W1, h, N);
    att_kernel<<<nblk, 256, 0, stream>>>(h, att_s1, att_d1, a_src, a_dst, N);
    agg_kernel<<<nblk, 256, 0, stream>>>(h, a_src, a_dst, row_ptr, sorted, b1, x2, N);
    // layer 2
    gemm_kernel<<<ggrid, 256, 0, stream>>>(x2, W2, h, N);
    att_kernel<<<nblk, 256, 0, stream>>>(h, att_s2, att_d2, a_src, a_dst, N);
    agg_kernel<<<nblk, 256, 0, stream>>>(h, a_src, a_dst, row_ptr, sorted, b2, out, N);
}

// Round 5
// 705.828 us; speedup vs baseline: 1.2610x; 1.2610x over previous
//
#include <hip/hip_runtime.h>
#include <hip/hip_bf16.h>

#define N_NODES 50000
#define N_EDGES 800000
// HEADS=4, OUT_CH=64, F=256 hard-coded. All harness I/O float32.

typedef __attribute__((ext_vector_type(8))) short short8;   // 8 bf16 = 4 VGPRs (MFMA A/B frag)
typedef __attribute__((ext_vector_type(4))) float floatx4;  // MFMA C/D frag

__device__ __forceinline__ ushort f2bf(float f) {           // RNE f32->bf16 bits
    uint u = __float_as_uint(f);
    uint r = u + 0x7FFFu + ((u >> 16) & 1u);
    return (ushort)(r >> 16);
}
__device__ __forceinline__ float bfu2f(ushort h) {
    return __uint_as_float(((uint)h) << 16);
}

// ---------------- CSR build (dst-sorted incoming edge lists) ----------------
__global__ void deg_kernel(const int* __restrict__ dst, int* __restrict__ cnt, int E) {
    int i = blockIdx.x * blockDim.x + threadIdx.x;
    if (i < E) atomicAdd(&cnt[dst[i]], 1);
}

__global__ void scan_kernel(const int* __restrict__ cnt, int* __restrict__ row_ptr,
                            int* __restrict__ row_tmp, int n) {
    __shared__ int sdata[1024];
    __shared__ int carry_s;
    if (threadIdx.x == 0) carry_s = 0;
    __syncthreads();
    for (int base = 0; base < n; base += 1024) {
        int i = base + threadIdx.x;
        int v = (i < n) ? cnt[i] : 0;
        sdata[threadIdx.x] = v;
        __syncthreads();
        for (int off = 1; off < 1024; off <<= 1) {
            int t = (threadIdx.x >= off) ? sdata[threadIdx.x - off] : 0;
            __syncthreads();
            sdata[threadIdx.x] += t;
            __syncthreads();
        }
        int carry = carry_s;
        int excl = carry + sdata[threadIdx.x] - v;
        if (i < n) { row_ptr[i] = excl; row_tmp[i] = excl; }
        __syncthreads();
        if (threadIdx.x == 1023) carry_s = carry + sdata[1023];
        __syncthreads();
    }
    if (threadIdx.x == 0) row_ptr[n] = carry_s;
}

__global__ void scatter_kernel(const int* __restrict__ src, const int* __restrict__ dst,
                               int* __restrict__ row_tmp, int* __restrict__ sorted_src, int E) {
    int i = blockIdx.x * blockDim.x + threadIdx.x;
    if (i < E) {
        int p = atomicAdd(&row_tmp[dst[i]], 1);
        sorted_src[p] = src[i];
    }
}

// ---------------- W prep: transpose + bf16 hi/lo split ----------------
// Wt[n][k] = W[k][n]; 256 blocks (k) x 256 threads (n).
__global__ void prep_w(const float* __restrict__ W, ushort* __restrict__ Wt_hi,
                       ushort* __restrict__ Wt_lo) {
    int n = threadIdx.x, k = blockIdx.x;
    float v = W[k * 256 + n];
    ushort hb = f2bf(v);
    Wt_hi[n * 256 + k] = hb;
    Wt_lo[n * 256 + k] = f2bf(v - bfu2f(hb));
}

// ---------------- GEMM: H_bf16[M,256] = A_f32[M,256] @ W[256,256] -----------
// bf16x3 split-precision MFMA: a_hi*b_hi + a_hi*b_lo + a_lo*b_hi.
// Block = 256 thr = 4 waves; block tile 64(M) x 256(N full); K-chunks of 32.
// MFMA 16x16x32 layouts (HW-verified, learn_hip m89/m120):
//   A: lane holds A[m=lane&15][k=(lane>>4)*8+j]
//   B: lane holds B[k=(lane>>4)*8+j][n=lane&15]
//   C/D: col=lane&15, row=(lane>>4)*4+reg
__global__ __launch_bounds__(256) void gemm_kernel(const float* __restrict__ A,
                                                   const ushort* __restrict__ Wt_hi,
                                                   const ushort* __restrict__ Wt_lo,
                                                   ushort* __restrict__ H, int M) {
    const int ROWP = 40;                       // LDS row pad: 32+8 elems (80 B, 16B-aligned)
    __shared__ ushort hi_s[256 * ROWP];        // 20 KB
    __shared__ ushort lo_s[256 * ROWP];        // 20 KB
    const int tid = threadIdx.x;
    const int wave = tid >> 6, lane = tid & 63;
    const int quad = lane >> 4, l16 = lane & 15;
    const int brow = blockIdx.x * 64;
    const int mrow = brow + wave * 16 + l16;
    const int mload = (mrow < M) ? mrow : (M - 1);   // clamp: result discarded by epilogue guard

    floatx4 acc[16];
    #pragma unroll
    for (int t = 0; t < 16; t++) acc[t] = (floatx4){0.f, 0.f, 0.f, 0.f};

    for (int k0 = 0; k0 < 256; k0 += 32) {
        __syncthreads();
        {   // stage Wt chunk [256 n][32 k] hi+lo; thread t = row n
            const ushort* gh = Wt_hi + tid * 256 + k0;
            const ushort* gl = Wt_lo + tid * 256 + k0;
            #pragma unroll
            for (int i = 0; i < 4; i++) {
                *reinterpret_cast<short8*>(&hi_s[tid * ROWP + i * 8]) =
                    *reinterpret_cast<const short8*>(gh + i * 8);
                *reinterpret_cast<short8*>(&lo_s[tid * ROWP + i * 8]) =
                    *reinterpret_cast<const short8*>(gl + i * 8);
            }
        }
        __syncthreads();
        // A fragment: 8 f32 from global, split to bf16 hi/lo in-register
        const float* ap = A + (size_t)mload * 256 + k0 + quad * 8;
        float4 a0 = *reinterpret_cast<const float4*>(ap);
        float4 a1 = *reinterpret_cast<const float4*>(ap + 4);
        float av[8] = {a0.x, a0.y, a0.z, a0.w, a1.x, a1.y, a1.z, a1.w};
        short8 a_hi, a_lo;
        #pragma unroll
        for (int j = 0; j < 8; j++) {
            ushort hb = f2bf(av[j]);
            a_hi[j] = (short)hb;
            a_lo[j] = (short)f2bf(av[j] - bfu2f(hb));
        }
        #pragma unroll
        for (int t = 0; t < 16; t++) {
            int roff = (t * 16 + l16) * ROWP + quad * 8;
            short8 b_hi = *reinterpret_cast<const short8*>(&hi_s[roff]);
            short8 b_lo = *reinterpret_cast<const short8*>(&lo_s[roff]);
            acc[t] = __builtin_amdgcn_mfma_f32_16x16x32_bf16(a_hi, b_hi, acc[t], 0, 0, 0);
            acc[t] = __builtin_amdgcn_mfma_f32_16x16x32_bf16(a_hi, b_lo, acc[t], 0, 0, 0);
            acc[t] = __builtin_amdgcn_mfma_f32_16x16x32_bf16(a_lo, b_hi, acc[t], 0, 0, 0);
        }
    }
    // epilogue: store bf16 h
    #pragma unroll
    for (int t = 0; t < 16; t++) {
        #pragma unroll
        for (int r = 0; r < 4; r++) {
            int m = brow + wave * 16 + quad * 4 + r;
            if (m < M) H[(size_t)m * 256 + t * 16 + l16] = f2bf(acc[t][r]);
        }
    }
}

// ---------------- attention logits: one wave per node ----------------
__global__ __launch_bounds__(256) void att_kernel(const ushort* __restrict__ H,
                                                  const float* __restrict__ att_s,
                                                  const float* __restrict__ att_d,
                                                  float* __restrict__ a_src,
                                                  float* __restrict__ a_dst, int N) {
    int wid = blockIdx.x * 4 + (threadIdx.x >> 6);
    int lane = threadIdx.x & 63;
    if (wid >= N) return;
    #pragma unroll
    for (int h = 0; h < 4; h++) {
        float v = bfu2f(H[(size_t)wid * 256 + h * 64 + lane]);
        float ps = v * att_s[h * 64 + lane];
        float pd = v * att_d[h * 64 + lane];
        #pragma unroll
        for (int off = 32; off > 0; off >>= 1) {
            ps += __shfl_xor(ps, off, 64);
            pd += __shfl_xor(pd, off, 64);
        }
        if (lane == 0) { a_src[wid * 4 + h] = ps; a_dst[wid * 4 + h] = pd; }
    }
}

// ---------------- per-dst softmax + weighted gather, one wave per node ------
__global__ __launch_bounds__(256) void agg_kernel(const ushort* __restrict__ H,
                                                  const float* __restrict__ a_src,
                                                  const float* __restrict__ a_dst,
                                                  const int* __restrict__ row_ptr,
                                                  const int* __restrict__ sorted_src,
                                                  const float* __restrict__ bias,
                                                  float* __restrict__ out, int N) {
    int i = blockIdx.x * 4 + (threadIdx.x >> 6);
    int lane = threadIdx.x & 63;
    if (i >= N) return;
    float ad[4], asi[4], m[4];
    #pragma unroll
    for (int h = 0; h < 4; h++) { ad[h] = a_dst[i * 4 + h]; asi[h] = a_src[i * 4 + h]; }
    #pragma unroll
    for (int h = 0; h < 4; h++) {
        float e = asi[h] + ad[h];
        m[h] = (e >= 0.f) ? e : 0.2f * e;   // self-loop logit
    }
    int start = row_ptr[i], end = row_ptr[i + 1];
    // pass 1: max over incoming edges (lane-parallel)
    for (int j = start + lane; j < end; j += 64) {
        int s = sorted_src[j];
        float4 av = *reinterpret_cast<const float4*>(a_src + (size_t)s * 4);
        float e;
        e = av.x + ad[0]; e = (e >= 0.f) ? e : 0.2f * e; m[0] = fmaxf(m[0], e);
        e = av.y + ad[1]; e = (e >= 0.f) ? e : 0.2f * e; m[1] = fmaxf(m[1], e);
        e = av.z + ad[2]; e = (e >= 0.f) ? e : 0.2f * e; m[2] = fmaxf(m[2], e);
        e = av.w + ad[3]; e = (e >= 0.f) ? e : 0.2f * e; m[3] = fmaxf(m[3], e);
    }
    #pragma unroll
    for (int h = 0; h < 4; h++)
        #pragma unroll
        for (int off = 32; off > 0; off >>= 1)
            m[h] = fmaxf(m[h], __shfl_xor(m[h], off, 64));
    // pass 2: weighted accumulation, lane = channel
    float acc[4] = {0.f, 0.f, 0.f, 0.f}, den[4] = {0.f, 0.f, 0.f, 0.f};
    {   // self loop
        const ushort* hr = H + (size_t)i * 256 + lane;
        #pragma unroll
        for (int h = 0; h < 4; h++) {
            float e = asi[h] + ad[h]; e = (e >= 0.f) ? e : 0.2f * e;
            float w = __expf(e - m[h]);
            den[h] += w;
            acc[h] += w * bfu2f(hr[h * 64]);
        }
    }
    for (int j = start; j < end; j++) {
        int s = sorted_src[j];
        float4 av = *reinterpret_cast<const float4*>(a_src + (size_t)s * 4);
        const ushort* hr = H + (size_t)s * 256 + lane;
        float e, w;
        e = av.x + ad[0]; e = (e >= 0.f) ? e : 0.2f * e; w = __expf(e - m[0]); den[0] += w; acc[0] += w * bfu2f(hr[0]);
        e = av.y + ad[1]; e = (e >= 0.f) ? e : 0.2f * e; w = __expf(e - m[1]); den[1] += w; acc[1] += w * bfu2f(hr[64]);
        e = av.z + ad[2]; e = (e >= 0.f) ? e : 0.2f * e; w = __expf(e - m[2]); den[2] += w; acc[2] += w * bfu2f(hr[128]);
        e = av.w + ad[3]; e = (e >= 0.f) ? e : 0.2f * e; w = __expf(e - m[3]); den[3] += w; acc[3] += w * bfu2f(hr[192]);
    }
    #pragma unroll
    for (int h = 0; h < 4; h++) {
        float v = acc[h] / (den[h] + 1e-16f) + bias[h * 64 + lane];
        v = (v > 0.f) ? v : expm1f(v);      // ELU
        out[(size_t)i * 256 + h * 64 + lane] = v;
    }
}

extern "C" void kernel_launch(void* const* d_in, const int* in_sizes, int n_in,
                              void* d_out, int out_size, void* d_ws, size_t ws_size,
                              hipStream_t stream) {
    const float* x      = (const float*)d_in[0];
    const int*   eidx   = (const int*)d_in[1];
    const float* W1     = (const float*)d_in[2];
    const float* att_s1 = (const float*)d_in[3];
    const float* att_d1 = (const float*)d_in[4];
    const float* b1     = (const float*)d_in[5];
    const float* W2     = (const float*)d_in[6];
    const float* att_s2 = (const float*)d_in[7];
    const float* att_d2 = (const float*)d_in[8];
    const float* b2     = (const float*)d_in[9];
    float* out = (float*)d_out;

    const int N = N_NODES, E = N_EDGES;
    char* ws = (char*)d_ws;
    size_t off = 0;
    auto alloc = [&](size_t bytes) -> void* {
        void* p = ws + off;
        off += (bytes + 255) & ~(size_t)255;
        return p;
    };
    // total ws ~ 31 MB (well inside known-good 57 MB envelope)
    ushort* h       = (ushort*)alloc((size_t)N * 256 * sizeof(ushort));  // 25.6 MB bf16
    float*  a_src   = (float*) alloc((size_t)N * 4 * sizeof(float));
    float*  a_dst   = (float*) alloc((size_t)N * 4 * sizeof(float));
    int*    cnt     = (int*)   alloc((size_t)N * sizeof(int));
    int*    row_ptr = (int*)   alloc((size_t)(N + 1) * sizeof(int));
    int*    row_tmp = (int*)   alloc((size_t)N * sizeof(int));
    int*    sorted  = (int*)   alloc((size_t)E * sizeof(int));
    ushort* Wt1_hi  = (ushort*)alloc(256 * 256 * sizeof(ushort));
    ushort* Wt1_lo  = (ushort*)alloc(256 * 256 * sizeof(ushort));
    ushort* Wt2_hi  = (ushort*)alloc(256 * 256 * sizeof(ushort));
    ushort* Wt2_lo  = (ushort*)alloc(256 * 256 * sizeof(ushort));
    float*  x2      = out;   // layer-1 f32 activations live in d_out, overwritten by layer 2
    (void)ws_size; (void)in_sizes; (void)n_in; (void)out_size;

    const int* e_src = eidx;
    const int* e_dst = eidx + E;

    // weight prep + CSR build
    prep_w<<<256, 256, 0, stream>>>(W1, Wt1_hi, Wt1_lo);
    prep_w<<<256, 256, 0, stream>>>(W2, Wt2_hi, Wt2_lo);
    hipMemsetAsync(cnt, 0, N * sizeof(int), stream);
    deg_kernel<<<(E + 255) / 256, 256, 0, stream>>>(e_dst, cnt, E);
    scan_kernel<<<1, 1024, 0, stream>>>(cnt, row_ptr, row_tmp, N);
    scatter_kernel<<<(E + 255) / 256, 256, 0, stream>>>(e_src, e_dst, row_tmp, sorted, E);

    int gblk = (N + 63) / 64;     // 782
    int nblk = (N + 3) / 4;       // 12500
    // layer 1
    gemm_kernel<<<gblk, 256, 0, stream>>>(x, Wt1_hi, Wt1_lo, h, N);
    att_kernel<<<nblk, 256, 0, stream>>>(h, att_s1, att_d1, a_src, a_dst, N);
    agg_kernel<<<nblk, 256, 0, stream>>>(h, a_src, a_dst, row_ptr, sorted, b1, x2, N);
    // layer 2
    gemm_kernel<<<gblk, 256, 0, stream>>>(x2, Wt2_hi, Wt2_lo, h, N);
    att_kernel<<<nblk, 256, 0, stream>>>(h, att_s2, att_d2, a_src, a_dst, N);
    agg_kernel<<<nblk, 256, 0, stream>>>(h, a_src, a_dst, row_ptr, sorted, b2, out, N);
}

// Round 6
// 564.872 us; speedup vs baseline: 1.5757x; 1.2495x over previous
//
#include <hip/hip_runtime.h>
#include <hip/hip_bf16.h>

#define N_NODES 50000
#define N_EDGES 800000
// HEADS=4, OUT_CH=64, F=256 hard-coded. All harness I/O float32.
// Internal H layout is INTERLEAVED: H[node*256 + c*4 + h]  (c=channel 0..63, h=head 0..3)

typedef __attribute__((ext_vector_type(8))) short short8;   // 8 bf16 = 4 VGPRs (MFMA A/B frag)
typedef __attribute__((ext_vector_type(4))) float floatx4;  // MFMA C/D frag

__device__ __forceinline__ ushort f2bf(float f) {           // RNE f32->bf16 bits
    uint u = __float_as_uint(f);
    uint r = u + 0x7FFFu + ((u >> 16) & 1u);
    return (ushort)(r >> 16);
}
__device__ __forceinline__ float bfu2f(ushort h) {
    return __uint_as_float(((uint)h) << 16);
}
__device__ __forceinline__ float lrelu(float e) { return e >= 0.f ? e : 0.2f * e; }

// ---------------- CSR build (dst-sorted incoming edge lists) ----------------
__global__ void deg_kernel(const int* __restrict__ dst, int* __restrict__ cnt, int E) {
    int i = blockIdx.x * blockDim.x + threadIdx.x;
    if (i < E) atomicAdd(&cnt[dst[i]], 1);
}

// 3-kernel multi-block exclusive scan of cnt[0..n) -> row_ptr/row_tmp
__global__ __launch_bounds__(256) void scan1_kernel(const int* __restrict__ cnt,
                                                    int* __restrict__ excl,
                                                    int* __restrict__ partial, int n) {
    __shared__ int sd[256];
    int tid = threadIdx.x;
    int i = blockIdx.x * 256 + tid;
    int v = (i < n) ? cnt[i] : 0;
    sd[tid] = v;
    __syncthreads();
    #pragma unroll
    for (int off = 1; off < 256; off <<= 1) {
        int t = (tid >= off) ? sd[tid - off] : 0;
        __syncthreads();
        sd[tid] += t;
        __syncthreads();
    }
    if (i < n) excl[i] = sd[tid] - v;
    if (tid == 255) partial[blockIdx.x] = sd[255];
}

__global__ __launch_bounds__(256) void scan2_kernel(int* __restrict__ partial, int nb) {
    __shared__ int sd[256];
    int tid = threadIdx.x;
    int v = (tid < nb) ? partial[tid] : 0;
    sd[tid] = v;
    __syncthreads();
    #pragma unroll
    for (int off = 1; off < 256; off <<= 1) {
        int t = (tid >= off) ? sd[tid - off] : 0;
        __syncthreads();
        sd[tid] += t;
        __syncthreads();
    }
    if (tid < nb) partial[tid] = sd[tid] - v;   // exclusive
}

__global__ __launch_bounds__(256) void scan3_kernel(const int* __restrict__ excl,
                                                    const int* __restrict__ partial,
                                                    int* __restrict__ row_ptr,
                                                    int* __restrict__ row_tmp, int n) {
    int i = blockIdx.x * 256 + threadIdx.x;
    if (i < n) {
        int v = excl[i] + partial[blockIdx.x];
        row_ptr[i] = v;
        row_tmp[i] = v;
    }
    if (i == 0) row_ptr[n] = N_EDGES;
}

__global__ void scatter_kernel(const int* __restrict__ src, const int* __restrict__ dst,
                               int* __restrict__ row_tmp, int* __restrict__ sorted_src, int E) {
    int i = blockIdx.x * blockDim.x + threadIdx.x;
    if (i < E) {
        int p = atomicAdd(&row_tmp[dst[i]], 1);
        sorted_src[p] = src[i];
    }
}

// ---------------- W prep: transpose + bf16 hi/lo split ----------------
__global__ void prep_w(const float* __restrict__ W, ushort* __restrict__ Wt_hi,
                       ushort* __restrict__ Wt_lo) {
    int n = threadIdx.x, k = blockIdx.x;
    float v = W[k * 256 + n];
    ushort hb = f2bf(v);
    Wt_hi[n * 256 + k] = hb;
    Wt_lo[n * 256 + k] = f2bf(v - bfu2f(hb));
}

// ---------------- GEMM: H_bf16[M,256] = A_f32[M,256] @ W[256,256] -----------
// bf16x3 split-precision MFMA. Output stored INTERLEAVED (c*4+h).
__global__ __launch_bounds__(256) void gemm_kernel(const float* __restrict__ A,
                                                   const ushort* __restrict__ Wt_hi,
                                                   const ushort* __restrict__ Wt_lo,
                                                   ushort* __restrict__ H, int M) {
    const int ROWP = 40;
    __shared__ ushort hi_s[256 * ROWP];
    __shared__ ushort lo_s[256 * ROWP];
    const int tid = threadIdx.x;
    const int wave = tid >> 6, lane = tid & 63;
    const int quad = lane >> 4, l16 = lane & 15;
    const int brow = blockIdx.x * 64;
    const int mrow = brow + wave * 16 + l16;
    const int mload = (mrow < M) ? mrow : (M - 1);

    floatx4 acc[16];
    #pragma unroll
    for (int t = 0; t < 16; t++) acc[t] = (floatx4){0.f, 0.f, 0.f, 0.f};

    for (int k0 = 0; k0 < 256; k0 += 32) {
        __syncthreads();
        {
            const ushort* gh = Wt_hi + tid * 256 + k0;
            const ushort* gl = Wt_lo + tid * 256 + k0;
            #pragma unroll
            for (int i = 0; i < 4; i++) {
                *reinterpret_cast<short8*>(&hi_s[tid * ROWP + i * 8]) =
                    *reinterpret_cast<const short8*>(gh + i * 8);
                *reinterpret_cast<short8*>(&lo_s[tid * ROWP + i * 8]) =
                    *reinterpret_cast<const short8*>(gl + i * 8);
            }
        }
        __syncthreads();
        const float* ap = A + (size_t)mload * 256 + k0 + quad * 8;
        float4 a0 = *reinterpret_cast<const float4*>(ap);
        float4 a1 = *reinterpret_cast<const float4*>(ap + 4);
        float av[8] = {a0.x, a0.y, a0.z, a0.w, a1.x, a1.y, a1.z, a1.w};
        short8 a_hi, a_lo;
        #pragma unroll
        for (int j = 0; j < 8; j++) {
            ushort hb = f2bf(av[j]);
            a_hi[j] = (short)hb;
            a_lo[j] = (short)f2bf(av[j] - bfu2f(hb));
        }
        #pragma unroll
        for (int t = 0; t < 16; t++) {
            int roff = (t * 16 + l16) * ROWP + quad * 8;
            short8 b_hi = *reinterpret_cast<const short8*>(&hi_s[roff]);
            short8 b_lo = *reinterpret_cast<const short8*>(&lo_s[roff]);
            acc[t] = __builtin_amdgcn_mfma_f32_16x16x32_bf16(a_hi, b_hi, acc[t], 0, 0, 0);
            acc[t] = __builtin_amdgcn_mfma_f32_16x16x32_bf16(a_hi, b_lo, acc[t], 0, 0, 0);
            acc[t] = __builtin_amdgcn_mfma_f32_16x16x32_bf16(a_lo, b_hi, acc[t], 0, 0, 0);
        }
    }
    // epilogue: store bf16 h, interleaved layout (c*4 + h)
    #pragma unroll
    for (int t = 0; t < 16; t++) {
        int col = t * 16 + l16;            // original channel index in [0,256)
        int c = col & 63, hh = col >> 6;
        #pragma unroll
        for (int r = 0; r < 4; r++) {
            int m = brow + wave * 16 + quad * 4 + r;
            if (m < M) H[(size_t)m * 256 + c * 4 + hh] = f2bf(acc[t][r]);
        }
    }
}

// ---------------- attention logits: one wave per node (interleaved H) -------
__global__ __launch_bounds__(256) void att_kernel(const ushort* __restrict__ H,
                                                  const float* __restrict__ att_s,
                                                  const float* __restrict__ att_d,
                                                  float* __restrict__ a_src,
                                                  float* __restrict__ a_dst, int N) {
    int wid = blockIdx.x * 4 + (threadIdx.x >> 6);
    int lane = threadIdx.x & 63;
    if (wid >= N) return;
    uint2 hv = *reinterpret_cast<const uint2*>(H + (size_t)wid * 256 + lane * 4);
    float v0 = __uint_as_float(hv.x << 16), v1 = __uint_as_float(hv.x & 0xffff0000u);
    float v2 = __uint_as_float(hv.y << 16), v3 = __uint_as_float(hv.y & 0xffff0000u);
    float ps0 = v0 * att_s[lane], ps1 = v1 * att_s[64 + lane];
    float ps2 = v2 * att_s[128 + lane], ps3 = v3 * att_s[192 + lane];
    float pd0 = v0 * att_d[lane], pd1 = v1 * att_d[64 + lane];
    float pd2 = v2 * att_d[128 + lane], pd3 = v3 * att_d[192 + lane];
    #pragma unroll
    for (int off = 32; off; off >>= 1) {
        ps0 += __shfl_xor(ps0, off, 64); ps1 += __shfl_xor(ps1, off, 64);
        ps2 += __shfl_xor(ps2, off, 64); ps3 += __shfl_xor(ps3, off, 64);
        pd0 += __shfl_xor(pd0, off, 64); pd1 += __shfl_xor(pd1, off, 64);
        pd2 += __shfl_xor(pd2, off, 64); pd3 += __shfl_xor(pd3, off, 64);
    }
    if (lane == 0) {
        a_src[wid * 4 + 0] = ps0; a_src[wid * 4 + 1] = ps1;
        a_src[wid * 4 + 2] = ps2; a_src[wid * 4 + 3] = ps3;
        a_dst[wid * 4 + 0] = pd0; a_dst[wid * 4 + 1] = pd1;
        a_dst[wid * 4 + 2] = pd2; a_dst[wid * 4 + 3] = pd3;
    }
}

// ---------------- per-dst softmax + weighted gather, one wave per node ------
// Phase A: lane j computes softmax weights for edge j (exp cost 1/64 of before).
// Phase B: broadcast (src, w0..w3) via __shfl; each lane does 1 uint2 load + 4 FMA.
__global__ __launch_bounds__(256) void agg_kernel(const ushort* __restrict__ H,
                                                  const float* __restrict__ a_src,
                                                  const float* __restrict__ a_dst,
                                                  const int* __restrict__ row_ptr,
                                                  const int* __restrict__ sorted_src,
                                                  const float* __restrict__ bias,
                                                  float* __restrict__ out, int N) {
    int wave = threadIdx.x >> 6, lane = threadIdx.x & 63;
    int i = blockIdx.x * 4 + wave;
    if (i >= N) return;
    float ad0 = a_dst[i * 4 + 0], ad1 = a_dst[i * 4 + 1];
    float ad2 = a_dst[i * 4 + 2], ad3 = a_dst[i * 4 + 3];
    float as0 = a_src[i * 4 + 0], as1 = a_src[i * 4 + 1];
    float as2 = a_src[i * 4 + 2], as3 = a_src[i * 4 + 3];
    float es0 = lrelu(as0 + ad0), es1 = lrelu(as1 + ad1);
    float es2 = lrelu(as2 + ad2), es3 = lrelu(as3 + ad3);
    float m0 = es0, m1 = es1, m2 = es2, m3 = es3;
    int start = row_ptr[i], end = row_ptr[i + 1];
    int deg = end - start;

    float e0 = 0.f, e1 = 0.f, e2 = 0.f, e3 = 0.f;
    int s_lane = 0;
    if (deg <= 64) {            // common case: cache edge data in registers
        if (lane < deg) {
            s_lane = sorted_src[start + lane];
            float4 av = *reinterpret_cast<const float4*>(a_src + (size_t)s_lane * 4);
            e0 = lrelu(av.x + ad0); e1 = lrelu(av.y + ad1);
            e2 = lrelu(av.z + ad2); e3 = lrelu(av.w + ad3);
            m0 = fmaxf(m0, e0); m1 = fmaxf(m1, e1);
            m2 = fmaxf(m2, e2); m3 = fmaxf(m3, e3);
        }
    } else {
        for (int j = start + lane; j < end; j += 64) {
            int s = sorted_src[j];
            float4 av = *reinterpret_cast<const float4*>(a_src + (size_t)s * 4);
            m0 = fmaxf(m0, lrelu(av.x + ad0)); m1 = fmaxf(m1, lrelu(av.y + ad1));
            m2 = fmaxf(m2, lrelu(av.z + ad2)); m3 = fmaxf(m3, lrelu(av.w + ad3));
        }
    }
    #pragma unroll
    for (int off = 32; off; off >>= 1) {
        m0 = fmaxf(m0, __shfl_xor(m0, off, 64)); m1 = fmaxf(m1, __shfl_xor(m1, off, 64));
        m2 = fmaxf(m2, __shfl_xor(m2, off, 64)); m3 = fmaxf(m3, __shfl_xor(m3, off, 64));
    }

    float acc0 = 0.f, acc1 = 0.f, acc2 = 0.f, acc3 = 0.f;
    float dp0 = 0.f, dp1 = 0.f, dp2 = 0.f, dp3 = 0.f;
    if (deg <= 64) {
        float w0 = 0.f, w1 = 0.f, w2 = 0.f, w3 = 0.f;
        if (lane < deg) {
            w0 = __expf(e0 - m0); w1 = __expf(e1 - m1);
            w2 = __expf(e2 - m2); w3 = __expf(e3 - m3);
            dp0 = w0; dp1 = w1; dp2 = w2; dp3 = w3;
        }
        for (int j = 0; j < deg; j++) {
            int sj = __shfl(s_lane, j, 64);
            float u0 = __shfl(w0, j, 64), u1 = __shfl(w1, j, 64);
            float u2 = __shfl(w2, j, 64), u3 = __shfl(w3, j, 64);
            uint2 hv = *reinterpret_cast<const uint2*>(H + (size_t)sj * 256 + lane * 4);
            acc0 += u0 * __uint_as_float(hv.x << 16);
            acc1 += u1 * __uint_as_float(hv.x & 0xffff0000u);
            acc2 += u2 * __uint_as_float(hv.y << 16);
            acc3 += u3 * __uint_as_float(hv.y & 0xffff0000u);
        }
    } else {
        for (int c0 = start; c0 < end; c0 += 64) {
            int nc = min(64, end - c0);
            float w0 = 0.f, w1 = 0.f, w2 = 0.f, w3 = 0.f;
            int sl = 0;
            if (lane < nc) {
                sl = sorted_src[c0 + lane];
                float4 av = *reinterpret_cast<const float4*>(a_src + (size_t)sl * 4);
                w0 = __expf(lrelu(av.x + ad0) - m0); w1 = __expf(lrelu(av.y + ad1) - m1);
                w2 = __expf(lrelu(av.z + ad2) - m2); w3 = __expf(lrelu(av.w + ad3) - m3);
                dp0 += w0; dp1 += w1; dp2 += w2; dp3 += w3;
            }
            for (int j = 0; j < nc; j++) {
                int sj = __shfl(sl, j, 64);
                float u0 = __shfl(w0, j, 64), u1 = __shfl(w1, j, 64);
                float u2 = __shfl(w2, j, 64), u3 = __shfl(w3, j, 64);
                uint2 hv = *reinterpret_cast<const uint2*>(H + (size_t)sj * 256 + lane * 4);
                acc0 += u0 * __uint_as_float(hv.x << 16);
                acc1 += u1 * __uint_as_float(hv.x & 0xffff0000u);
                acc2 += u2 * __uint_as_float(hv.y << 16);
                acc3 += u3 * __uint_as_float(hv.y & 0xffff0000u);
            }
        }
    }
    // reduce den partials across lanes
    #pragma unroll
    for (int off = 32; off; off >>= 1) {
        dp0 += __shfl_xor(dp0, off, 64); dp1 += __shfl_xor(dp1, off, 64);
        dp2 += __shfl_xor(dp2, off, 64); dp3 += __shfl_xor(dp3, off, 64);
    }
    // self loop (lane-uniform weights, added after reduction)
    float ws0 = __expf(es0 - m0), ws1 = __expf(es1 - m1);
    float ws2 = __expf(es2 - m2), ws3 = __expf(es3 - m3);
    {
        uint2 hv = *reinterpret_cast<const uint2*>(H + (size_t)i * 256 + lane * 4);
        acc0 += ws0 * __uint_as_float(hv.x << 16);
        acc1 += ws1 * __uint_as_float(hv.x & 0xffff0000u);
        acc2 += ws2 * __uint_as_float(hv.y << 16);
        acc3 += ws3 * __uint_as_float(hv.y & 0xffff0000u);
    }
    float den0 = dp0 + ws0, den1 = dp1 + ws1, den2 = dp2 + ws2, den3 = dp3 + ws3;
    // epilogue: reference layout out[n][h*64+c]
    float v;
    v = acc0 / (den0 + 1e-16f) + bias[lane];        v = (v > 0.f) ? v : expm1f(v); out[(size_t)i * 256 + lane]       = v;
    v = acc1 / (den1 + 1e-16f) + bias[64 + lane];   v = (v > 0.f) ? v : expm1f(v); out[(size_t)i * 256 + 64 + lane]  = v;
    v = acc2 / (den2 + 1e-16f) + bias[128 + lane];  v = (v > 0.f) ? v : expm1f(v); out[(size_t)i * 256 + 128 + lane] = v;
    v = acc3 / (den3 + 1e-16f) + bias[192 + lane];  v = (v > 0.f) ? v : expm1f(v); out[(size_t)i * 256 + 192 + lane] = v;
}

extern "C" void kernel_launch(void* const* d_in, const int* in_sizes, int n_in,
                              void* d_out, int out_size, void* d_ws, size_t ws_size,
                              hipStream_t stream) {
    const float* x      = (const float*)d_in[0];
    const int*   eidx   = (const int*)d_in[1];
    const float* W1     = (const float*)d_in[2];
    const float* att_s1 = (const float*)d_in[3];
    const float* att_d1 = (const float*)d_in[4];
    const float* b1     = (const float*)d_in[5];
    const float* W2     = (const float*)d_in[6];
    const float* att_s2 = (const float*)d_in[7];
    const float* att_d2 = (const float*)d_in[8];
    const float* b2     = (const float*)d_in[9];
    float* out = (float*)d_out;

    const int N = N_NODES, E = N_EDGES;
    char* ws = (char*)d_ws;
    size_t off = 0;
    auto alloc = [&](size_t bytes) -> void* {
        void* p = ws + off;
        off += (bytes + 255) & ~(size_t)255;
        return p;
    };
    ushort* h       = (ushort*)alloc((size_t)N * 256 * sizeof(ushort));  // 25.6 MB bf16
    float*  a_src   = (float*) alloc((size_t)N * 4 * sizeof(float));
    float*  a_dst   = (float*) alloc((size_t)N * 4 * sizeof(float));
    int*    cnt     = (int*)   alloc((size_t)N * sizeof(int));
    int*    row_ptr = (int*)   alloc((size_t)(N + 1) * sizeof(int));
    int*    row_tmp = (int*)   alloc((size_t)N * sizeof(int));
    int*    sorted  = (int*)   alloc((size_t)E * sizeof(int));
    int*    excl    = (int*)   alloc((size_t)N * sizeof(int));
    int*    partial = (int*)   alloc(256 * sizeof(int));
    ushort* Wt1_hi  = (ushort*)alloc(256 * 256 * sizeof(ushort));
    ushort* Wt1_lo  = (ushort*)alloc(256 * 256 * sizeof(ushort));
    ushort* Wt2_hi  = (ushort*)alloc(256 * 256 * sizeof(ushort));
    ushort* Wt2_lo  = (ushort*)alloc(256 * 256 * sizeof(ushort));
    float*  x2      = out;   // layer-1 f32 activations live in d_out, overwritten by layer 2
    (void)ws_size; (void)in_sizes; (void)n_in; (void)out_size;

    const int* e_src = eidx;
    const int* e_dst = eidx + E;
    const int nsb = (N + 255) / 256;   // 196 scan blocks

    // weight prep + CSR build
    prep_w<<<256, 256, 0, stream>>>(W1, Wt1_hi, Wt1_lo);
    prep_w<<<256, 256, 0, stream>>>(W2, Wt2_hi, Wt2_lo);
    hipMemsetAsync(cnt, 0, N * sizeof(int), stream);
    deg_kernel<<<(E + 255) / 256, 256, 0, stream>>>(e_dst, cnt, E);
    scan1_kernel<<<nsb, 256, 0, stream>>>(cnt, excl, partial, N);
    scan2_kernel<<<1, 256, 0, stream>>>(partial, nsb);
    scan3_kernel<<<nsb, 256, 0, stream>>>(excl, partial, row_ptr, row_tmp, N);
    scatter_kernel<<<(E + 255) / 256, 256, 0, stream>>>(e_src, e_dst, row_tmp, sorted, E);

    int gblk = (N + 63) / 64;     // 782
    int nblk = (N + 3) / 4;       // 12500
    // layer 1
    gemm_kernel<<<gblk, 256, 0, stream>>>(x, Wt1_hi, Wt1_lo, h, N);
    att_kernel<<<nblk, 256, 0, stream>>>(h, att_s1, att_d1, a_src, a_dst, N);
    agg_kernel<<<nblk, 256, 0, stream>>>(h, a_src, a_dst, row_ptr, sorted, b1, x2, N);
    // layer 2
    gemm_kernel<<<gblk, 256, 0, stream>>>(x2, Wt2_hi, Wt2_lo, h, N);
    att_kernel<<<nblk, 256, 0, stream>>>(h, att_s2, att_d2, a_src, a_dst, N);
    agg_kernel<<<nblk, 256, 0, stream>>>(h, a_src, a_dst, row_ptr, sorted, b2, out, N);
}

// Round 7
// 500.945 us; speedup vs baseline: 1.7768x; 1.1276x over previous
//
#include <hip/hip_runtime.h>
#include <hip/hip_bf16.h>

#define N_NODES 50000
#define N_EDGES 800000
// HEADS=4, OUT_CH=64, F=256 hard-coded. All harness I/O float32.
// Internal H layout INTERLEAVED: H[node*256 + c*4 + h]  (c=channel 0..63, h=head 0..3)

typedef __attribute__((ext_vector_type(8))) short short8;   // 8 bf16 = 4 VGPRs (MFMA A/B frag)
typedef __attribute__((ext_vector_type(4))) float floatx4;  // MFMA C/D frag

__device__ __forceinline__ ushort f2bf(float f) {           // RNE f32->bf16 bits
    uint u = __float_as_uint(f);
    uint r = u + 0x7FFFu + ((u >> 16) & 1u);
    return (ushort)(r >> 16);
}
__device__ __forceinline__ float bfu2f(ushort h) {
    return __uint_as_float(((uint)h) << 16);
}
__device__ __forceinline__ float bflo(uint u) { return __uint_as_float(u << 16); }
__device__ __forceinline__ float bfhi(uint u) { return __uint_as_float(u & 0xffff0000u); }
__device__ __forceinline__ float lrelu(float e) { return e >= 0.f ? e : 0.2f * e; }

// ---------------- CSR build (dst-sorted incoming edge lists) ----------------
__global__ void deg_kernel(const int* __restrict__ dst, int* __restrict__ cnt, int E) {
    int i = blockIdx.x * blockDim.x + threadIdx.x;
    if (i < E) atomicAdd(&cnt[dst[i]], 1);
}

__global__ __launch_bounds__(256) void scan1_kernel(const int* __restrict__ cnt,
                                                    int* __restrict__ excl,
                                                    int* __restrict__ partial, int n) {
    __shared__ int sd[256];
    int tid = threadIdx.x;
    int i = blockIdx.x * 256 + tid;
    int v = (i < n) ? cnt[i] : 0;
    sd[tid] = v;
    __syncthreads();
    #pragma unroll
    for (int off = 1; off < 256; off <<= 1) {
        int t = (tid >= off) ? sd[tid - off] : 0;
        __syncthreads();
        sd[tid] += t;
        __syncthreads();
    }
    if (i < n) excl[i] = sd[tid] - v;
    if (tid == 255) partial[blockIdx.x] = sd[255];
}

__global__ __launch_bounds__(256) void scan2_kernel(int* __restrict__ partial, int nb) {
    __shared__ int sd[256];
    int tid = threadIdx.x;
    int v = (tid < nb) ? partial[tid] : 0;
    sd[tid] = v;
    __syncthreads();
    #pragma unroll
    for (int off = 1; off < 256; off <<= 1) {
        int t = (tid >= off) ? sd[tid - off] : 0;
        __syncthreads();
        sd[tid] += t;
        __syncthreads();
    }
    if (tid < nb) partial[tid] = sd[tid] - v;   // exclusive
}

__global__ __launch_bounds__(256) void scan3_kernel(const int* __restrict__ excl,
                                                    const int* __restrict__ partial,
                                                    int* __restrict__ row_ptr,
                                                    int* __restrict__ row_tmp, int n) {
    int i = blockIdx.x * 256 + threadIdx.x;
    if (i < n) {
        int v = excl[i] + partial[blockIdx.x];
        row_ptr[i] = v;
        row_tmp[i] = v;
    }
    if (i == 0) row_ptr[n] = N_EDGES;
}

__global__ void scatter_kernel(const int* __restrict__ src, const int* __restrict__ dst,
                               int* __restrict__ row_tmp, int* __restrict__ sorted_src, int E) {
    int i = blockIdx.x * blockDim.x + threadIdx.x;
    if (i < E) {
        int p = atomicAdd(&row_tmp[dst[i]], 1);
        sorted_src[p] = src[i];
    }
}

// ---------------- W prep: transpose + bf16 hi/lo split, both layers ---------
__global__ void prep_w(const float* __restrict__ W1, const float* __restrict__ W2,
                       ushort* __restrict__ Wt1_hi, ushort* __restrict__ Wt1_lo,
                       ushort* __restrict__ Wt2_hi, ushort* __restrict__ Wt2_lo) {
    int n = threadIdx.x, k = blockIdx.x & 255;
    const float* W = (blockIdx.x < 256) ? W1 : W2;
    ushort* Wh = (blockIdx.x < 256) ? Wt1_hi : Wt2_hi;
    ushort* Wl = (blockIdx.x < 256) ? Wt1_lo : Wt2_lo;
    float v = W[k * 256 + n];
    ushort hb = f2bf(v);
    Wh[n * 256 + k] = hb;
    Wl[n * 256 + k] = f2bf(v - bfu2f(hb));
}

// ------- GEMM + fused attention logits -------
// H_bf16[M,256] = A_f32[M,256] @ W[256,256] (bf16x3 split MFMA), stored interleaved.
// a_src[m,h] = sum_c H[m,h*64+c]*att_s[h*64+c], a_dst likewise — computed from acc
// in-register (head of col t*16+l16 is t>>2).
__global__ __launch_bounds__(256) void gemm_att_kernel(const float* __restrict__ A,
                                                       const ushort* __restrict__ Wt_hi,
                                                       const ushort* __restrict__ Wt_lo,
                                                       const float* __restrict__ att_s,
                                                       const float* __restrict__ att_d,
                                                       ushort* __restrict__ H,
                                                       float* __restrict__ a_src,
                                                       float* __restrict__ a_dst, int M) {
    const int ROWP = 40;
    __shared__ ushort hi_s[256 * ROWP];
    __shared__ ushort lo_s[256 * ROWP];
    const int tid = threadIdx.x;
    const int wave = tid >> 6, lane = tid & 63;
    const int quad = lane >> 4, l16 = lane & 15;
    const int brow = blockIdx.x * 64;
    const int mrow = brow + wave * 16 + l16;
    const int mload = (mrow < M) ? mrow : (M - 1);

    floatx4 acc[16];
    #pragma unroll
    for (int t = 0; t < 16; t++) acc[t] = (floatx4){0.f, 0.f, 0.f, 0.f};

    for (int k0 = 0; k0 < 256; k0 += 32) {
        __syncthreads();
        {
            const ushort* gh = Wt_hi + tid * 256 + k0;
            const ushort* gl = Wt_lo + tid * 256 + k0;
            #pragma unroll
            for (int i = 0; i < 4; i++) {
                *reinterpret_cast<short8*>(&hi_s[tid * ROWP + i * 8]) =
                    *reinterpret_cast<const short8*>(gh + i * 8);
                *reinterpret_cast<short8*>(&lo_s[tid * ROWP + i * 8]) =
                    *reinterpret_cast<const short8*>(gl + i * 8);
            }
        }
        __syncthreads();
        const float* ap = A + (size_t)mload * 256 + k0 + quad * 8;
        float4 a0 = *reinterpret_cast<const float4*>(ap);
        float4 a1 = *reinterpret_cast<const float4*>(ap + 4);
        float av[8] = {a0.x, a0.y, a0.z, a0.w, a1.x, a1.y, a1.z, a1.w};
        short8 a_hi, a_lo;
        #pragma unroll
        for (int j = 0; j < 8; j++) {
            ushort hb = f2bf(av[j]);
            a_hi[j] = (short)hb;
            a_lo[j] = (short)f2bf(av[j] - bfu2f(hb));
        }
        #pragma unroll
        for (int t = 0; t < 16; t++) {
            int roff = (t * 16 + l16) * ROWP + quad * 8;
            short8 b_hi = *reinterpret_cast<const short8*>(&hi_s[roff]);
            short8 b_lo = *reinterpret_cast<const short8*>(&lo_s[roff]);
            acc[t] = __builtin_amdgcn_mfma_f32_16x16x32_bf16(a_hi, b_hi, acc[t], 0, 0, 0);
            acc[t] = __builtin_amdgcn_mfma_f32_16x16x32_bf16(a_hi, b_lo, acc[t], 0, 0, 0);
            acc[t] = __builtin_amdgcn_mfma_f32_16x16x32_bf16(a_lo, b_hi, acc[t], 0, 0, 0);
        }
    }
    // fused attention-logit partials: head of col (t*16+l16) is t>>2
    float ps[4][4] = {}, pd[4][4] = {};
    #pragma unroll
    for (int t = 0; t < 16; t++) {
        int hh = t >> 2;
        float as_v = att_s[t * 16 + l16];
        float ad_v = att_d[t * 16 + l16];
        #pragma unroll
        for (int r = 0; r < 4; r++) {
            ps[hh][r] += acc[t][r] * as_v;
            pd[hh][r] += acc[t][r] * ad_v;
        }
    }
    #pragma unroll
    for (int off = 1; off < 16; off <<= 1) {
        #pragma unroll
        for (int hh = 0; hh < 4; hh++)
            #pragma unroll
            for (int r = 0; r < 4; r++) {
                ps[hh][r] += __shfl_xor(ps[hh][r], off, 64);
                pd[hh][r] += __shfl_xor(pd[hh][r], off, 64);
            }
    }
    if (l16 == 0) {
        #pragma unroll
        for (int r = 0; r < 4; r++) {
            int m = brow + wave * 16 + quad * 4 + r;
            if (m < M) {
                #pragma unroll
                for (int hh = 0; hh < 4; hh++) {
                    a_src[m * 4 + hh] = ps[hh][r];
                    a_dst[m * 4 + hh] = pd[hh][r];
                }
            }
        }
    }
    // store bf16 H, interleaved (c*4 + h)
    #pragma unroll
    for (int t = 0; t < 16; t++) {
        int col = t * 16 + l16;
        int c = col & 63, hh = col >> 6;
        #pragma unroll
        for (int r = 0; r < 4; r++) {
            int m = brow + wave * 16 + quad * 4 + r;
            if (m < M) H[(size_t)m * 256 + c * 4 + hh] = f2bf(acc[t][r]);
        }
    }
}

// ---------------- per-dst softmax + weighted gather, one wave per node ------
// Phase A: lane j computes softmax weights for edge j.
// Phase B: two 32-lane halves process edge pairs (half h takes edge 2t+h);
// each lane covers channels {2*hl, 2*hl+1} x 4 heads via one uint4 load.
__global__ __launch_bounds__(256) void agg_kernel(const ushort* __restrict__ H,
                                                  const float* __restrict__ a_src,
                                                  const float* __restrict__ a_dst,
                                                  const int* __restrict__ row_ptr,
                                                  const int* __restrict__ sorted_src,
                                                  const float* __restrict__ bias,
                                                  float* __restrict__ out, int N) {
    int wave = threadIdx.x >> 6, lane = threadIdx.x & 63;
    int half = lane >> 5, hl = lane & 31;
    int i = blockIdx.x * 4 + wave;
    if (i >= N) return;
    float ad0 = a_dst[i * 4 + 0], ad1 = a_dst[i * 4 + 1];
    float ad2 = a_dst[i * 4 + 2], ad3 = a_dst[i * 4 + 3];
    float as0 = a_src[i * 4 + 0], as1 = a_src[i * 4 + 1];
    float as2 = a_src[i * 4 + 2], as3 = a_src[i * 4 + 3];
    float es0 = lrelu(as0 + ad0), es1 = lrelu(as1 + ad1);
    float es2 = lrelu(as2 + ad2), es3 = lrelu(as3 + ad3);
    float m0 = es0, m1 = es1, m2 = es2, m3 = es3;
    int start = row_ptr[i], end = row_ptr[i + 1];
    int deg = end - start;

    // accumulators: channels c=2*hl (a*) and c=2*hl+1 (b*), per head
    float a0 = 0.f, a1 = 0.f, a2 = 0.f, a3 = 0.f;
    float b0 = 0.f, b1 = 0.f, b2 = 0.f, b3 = 0.f;
    float dp0 = 0.f, dp1 = 0.f, dp2 = 0.f, dp3 = 0.f;

    if (deg <= 64) {
        float e0 = 0.f, e1 = 0.f, e2 = 0.f, e3 = 0.f;
        int s_lane = 0;
        if (lane < deg) {
            s_lane = sorted_src[start + lane];
            float4 av = *reinterpret_cast<const float4*>(a_src + (size_t)s_lane * 4);
            e0 = lrelu(av.x + ad0); e1 = lrelu(av.y + ad1);
            e2 = lrelu(av.z + ad2); e3 = lrelu(av.w + ad3);
            m0 = fmaxf(m0, e0); m1 = fmaxf(m1, e1);
            m2 = fmaxf(m2, e2); m3 = fmaxf(m3, e3);
        }
        #pragma unroll
        for (int off = 32; off; off >>= 1) {
            m0 = fmaxf(m0, __shfl_xor(m0, off, 64)); m1 = fmaxf(m1, __shfl_xor(m1, off, 64));
            m2 = fmaxf(m2, __shfl_xor(m2, off, 64)); m3 = fmaxf(m3, __shfl_xor(m3, off, 64));
        }
        float w0 = 0.f, w1 = 0.f, w2 = 0.f, w3 = 0.f;
        if (lane < deg) {
            w0 = __expf(e0 - m0); w1 = __expf(e1 - m1);
            w2 = __expf(e2 - m2); w3 = __expf(e3 - m3);
            dp0 = w0; dp1 = w1; dp2 = w2; dp3 = w3;
        }
        int npair = (deg + 1) >> 1;
        for (int t = 0; t < npair; t++) {
            int j = 2 * t + half;          // lanes j>=deg hold w=0, s=0 (safe)
            int sj = __shfl(s_lane, j, 64);
            float u0 = __shfl(w0, j, 64), u1 = __shfl(w1, j, 64);
            float u2 = __shfl(w2, j, 64), u3 = __shfl(w3, j, 64);
            uint4 hv = *reinterpret_cast<const uint4*>(H + (size_t)sj * 256 + hl * 8);
            a0 += u0 * bflo(hv.x); a1 += u1 * bfhi(hv.x);
            a2 += u2 * bflo(hv.y); a3 += u3 * bfhi(hv.y);
            b0 += u0 * bflo(hv.z); b1 += u1 * bfhi(hv.z);
            b2 += u2 * bflo(hv.w); b3 += u3 * bfhi(hv.w);
        }
    } else {
        for (int j = start + lane; j < end; j += 64) {
            int s = sorted_src[j];
            float4 av = *reinterpret_cast<const float4*>(a_src + (size_t)s * 4);
            m0 = fmaxf(m0, lrelu(av.x + ad0)); m1 = fmaxf(m1, lrelu(av.y + ad1));
            m2 = fmaxf(m2, lrelu(av.z + ad2)); m3 = fmaxf(m3, lrelu(av.w + ad3));
        }
        #pragma unroll
        for (int off = 32; off; off >>= 1) {
            m0 = fmaxf(m0, __shfl_xor(m0, off, 64)); m1 = fmaxf(m1, __shfl_xor(m1, off, 64));
            m2 = fmaxf(m2, __shfl_xor(m2, off, 64)); m3 = fmaxf(m3, __shfl_xor(m3, off, 64));
        }
        for (int c0 = start; c0 < end; c0 += 64) {
            int nc = min(64, end - c0);
            float w0 = 0.f, w1 = 0.f, w2 = 0.f, w3 = 0.f;
            int sl = 0;
            if (lane < nc) {
                sl = sorted_src[c0 + lane];
                float4 av = *reinterpret_cast<const float4*>(a_src + (size_t)sl * 4);
                w0 = __expf(lrelu(av.x + ad0) - m0); w1 = __expf(lrelu(av.y + ad1) - m1);
                w2 = __expf(lrelu(av.z + ad2) - m2); w3 = __expf(lrelu(av.w + ad3) - m3);
                dp0 += w0; dp1 += w1; dp2 += w2; dp3 += w3;
            }
            int npair = (nc + 1) >> 1;
            for (int t = 0; t < npair; t++) {
                int j = 2 * t + half;
                int sj = __shfl(sl, j, 64);
                float u0 = __shfl(w0, j, 64), u1 = __shfl(w1, j, 64);
                float u2 = __shfl(w2, j, 64), u3 = __shfl(w3, j, 64);
                uint4 hv = *reinterpret_cast<const uint4*>(H + (size_t)sj * 256 + hl * 8);
                a0 += u0 * bflo(hv.x); a1 += u1 * bfhi(hv.x);
                a2 += u2 * bflo(hv.y); a3 += u3 * bfhi(hv.y);
                b0 += u0 * bflo(hv.z); b1 += u1 * bfhi(hv.z);
                b2 += u2 * bflo(hv.w); b3 += u3 * bfhi(hv.w);
            }
        }
    }
    // merge the two halves (they processed disjoint edges, same channels)
    a0 += __shfl_xor(a0, 32, 64); a1 += __shfl_xor(a1, 32, 64);
    a2 += __shfl_xor(a2, 32, 64); a3 += __shfl_xor(a3, 32, 64);
    b0 += __shfl_xor(b0, 32, 64); b1 += __shfl_xor(b1, 32, 64);
    b2 += __shfl_xor(b2, 32, 64); b3 += __shfl_xor(b3, 32, 64);
    // reduce den partials across all lanes
    #pragma unroll
    for (int off = 32; off; off >>= 1) {
        dp0 += __shfl_xor(dp0, off, 64); dp1 += __shfl_xor(dp1, off, 64);
        dp2 += __shfl_xor(dp2, off, 64); dp3 += __shfl_xor(dp3, off, 64);
    }
    // self loop (lane-uniform weights)
    float ws0 = __expf(es0 - m0), ws1 = __expf(es1 - m1);
    float ws2 = __expf(es2 - m2), ws3 = __expf(es3 - m3);
    {
        uint4 hv = *reinterpret_cast<const uint4*>(H + (size_t)i * 256 + hl * 8);
        a0 += ws0 * bflo(hv.x); a1 += ws1 * bfhi(hv.x);
        a2 += ws2 * bflo(hv.y); a3 += ws3 * bfhi(hv.y);
        b0 += ws0 * bflo(hv.z); b1 += ws1 * bfhi(hv.z);
        b2 += ws2 * bflo(hv.w); b3 += ws3 * bfhi(hv.w);
    }
    if (half == 0) {
        float r0 = 1.f / (dp0 + ws0 + 1e-16f), r1 = 1.f / (dp1 + ws1 + 1e-16f);
        float r2 = 1.f / (dp2 + ws2 + 1e-16f), r3 = 1.f / (dp3 + ws3 + 1e-16f);
        float2 o;
        float* op = out + (size_t)i * 256 + hl * 2;
        float v;
        v = a0 * r0 + bias[2 * hl];       o.x = (v > 0.f) ? v : expm1f(v);
        v = b0 * r0 + bias[2 * hl + 1];   o.y = (v > 0.f) ? v : expm1f(v);
        *reinterpret_cast<float2*>(op) = o;
        v = a1 * r1 + bias[64 + 2 * hl];     o.x = (v > 0.f) ? v : expm1f(v);
        v = b1 * r1 + bias[64 + 2 * hl + 1]; o.y = (v > 0.f) ? v : expm1f(v);
        *reinterpret_cast<float2*>(op + 64) = o;
        v = a2 * r2 + bias[128 + 2 * hl];     o.x = (v > 0.f) ? v : expm1f(v);
        v = b2 * r2 + bias[128 + 2 * hl + 1]; o.y = (v > 0.f) ? v : expm1f(v);
        *reinterpret_cast<float2*>(op + 128) = o;
        v = a3 * r3 + bias[192 + 2 * hl];     o.x = (v > 0.f) ? v : expm1f(v);
        v = b3 * r3 + bias[192 + 2 * hl + 1]; o.y = (v > 0.f) ? v : expm1f(v);
        *reinterpret_cast<float2*>(op + 192) = o;
    }
}

extern "C" void kernel_launch(void* const* d_in, const int* in_sizes, int n_in,
                              void* d_out, int out_size, void* d_ws, size_t ws_size,
                              hipStream_t stream) {
    const float* x      = (const float*)d_in[0];
    const int*   eidx   = (const int*)d_in[1];
    const float* W1     = (const float*)d_in[2];
    const float* att_s1 = (const float*)d_in[3];
    const float* att_d1 = (const float*)d_in[4];
    const float* b1     = (const float*)d_in[5];
    const float* W2     = (const float*)d_in[6];
    const float* att_s2 = (const float*)d_in[7];
    const float* att_d2 = (const float*)d_in[8];
    const float* b2     = (const float*)d_in[9];
    float* out = (float*)d_out;

    const int N = N_NODES, E = N_EDGES;
    char* ws = (char*)d_ws;
    size_t off = 0;
    auto alloc = [&](size_t bytes) -> void* {
        void* p = ws + off;
        off += (bytes + 255) & ~(size_t)255;
        return p;
    };
    ushort* h       = (ushort*)alloc((size_t)N * 256 * sizeof(ushort));  // 25.6 MB bf16
    float*  a_src   = (float*) alloc((size_t)N * 4 * sizeof(float));
    float*  a_dst   = (float*) alloc((size_t)N * 4 * sizeof(float));
    int*    cnt     = (int*)   alloc((size_t)N * sizeof(int));
    int*    row_ptr = (int*)   alloc((size_t)(N + 1) * sizeof(int));
    int*    row_tmp = (int*)   alloc((size_t)N * sizeof(int));
    int*    sorted  = (int*)   alloc((size_t)E * sizeof(int));
    int*    excl    = (int*)   alloc((size_t)N * sizeof(int));
    int*    partial = (int*)   alloc(256 * sizeof(int));
    ushort* Wt1_hi  = (ushort*)alloc(256 * 256 * sizeof(ushort));
    ushort* Wt1_lo  = (ushort*)alloc(256 * 256 * sizeof(ushort));
    ushort* Wt2_hi  = (ushort*)alloc(256 * 256 * sizeof(ushort));
    ushort* Wt2_lo  = (ushort*)alloc(256 * 256 * sizeof(ushort));
    float*  x2      = out;   // layer-1 f32 activations live in d_out, overwritten by layer 2
    (void)ws_size; (void)in_sizes; (void)n_in; (void)out_size;

    const int* e_src = eidx;
    const int* e_dst = eidx + E;
    const int nsb = (N + 255) / 256;   // 196 scan blocks

    prep_w<<<512, 256, 0, stream>>>(W1, W2, Wt1_hi, Wt1_lo, Wt2_hi, Wt2_lo);
    hipMemsetAsync(cnt, 0, N * sizeof(int), stream);
    deg_kernel<<<(E + 255) / 256, 256, 0, stream>>>(e_dst, cnt, E);
    scan1_kernel<<<nsb, 256, 0, stream>>>(cnt, excl, partial, N);
    scan2_kernel<<<1, 256, 0, stream>>>(partial, nsb);
    scan3_kernel<<<nsb, 256, 0, stream>>>(excl, partial, row_ptr, row_tmp, N);
    scatter_kernel<<<(E + 255) / 256, 256, 0, stream>>>(e_src, e_dst, row_tmp, sorted, E);

    int gblk = (N + 63) / 64;     // 782
    int nblk = (N + 3) / 4;       // 12500
    // layer 1
    gemm_att_kernel<<<gblk, 256, 0, stream>>>(x, Wt1_hi, Wt1_lo, att_s1, att_d1,
                                              h, a_src, a_dst, N);
    agg_kernel<<<nblk, 256, 0, stream>>>(h, a_src, a_dst, row_ptr, sorted, b1, x2, N);
    // layer 2
    gemm_att_kernel<<<gblk, 256, 0, stream>>>(x2, Wt2_hi, Wt2_lo, att_s2, att_d2,
                                              h, a_src, a_dst, N);
    agg_kernel<<<nblk, 256, 0, stream>>>(h, a_src, a_dst, row_ptr, sorted, b2, out, N);
}

// Round 8
// 475.295 us; speedup vs baseline: 1.8727x; 1.0540x over previous
//
#include <hip/hip_runtime.h>
#include <hip/hip_bf16.h>

#define N_NODES 50000
#define N_EDGES 800000
// HEADS=4, OUT_CH=64, F=256 hard-coded. All harness I/O float32.
// Internal H layout INTERLEAVED: H[node*256 + c*4 + h]  (c=channel 0..63, h=head 0..3)

typedef __attribute__((ext_vector_type(8))) short short8;   // 8 bf16 = 4 VGPRs (MFMA A/B frag)
typedef __attribute__((ext_vector_type(4))) float floatx4;  // MFMA C/D frag

__device__ __forceinline__ ushort f2bf(float f) {           // RNE f32->bf16 bits
    uint u = __float_as_uint(f);
    uint r = u + 0x7FFFu + ((u >> 16) & 1u);
    return (ushort)(r >> 16);
}
__device__ __forceinline__ float bfu2f(ushort h) {
    return __uint_as_float(((uint)h) << 16);
}
__device__ __forceinline__ float bflo(uint u) { return __uint_as_float(u << 16); }
__device__ __forceinline__ float bfhi(uint u) { return __uint_as_float(u & 0xffff0000u); }
__device__ __forceinline__ float lrelu(float e) { return e >= 0.f ? e : 0.2f * e; }

// ---------------- CSR build (dst-sorted incoming edge lists) ----------------
__global__ void deg_kernel(const int* __restrict__ dst, int* __restrict__ cnt, int E) {
    int i = blockIdx.x * blockDim.x + threadIdx.x;
    if (i < E) atomicAdd(&cnt[dst[i]], 1);
}

__global__ __launch_bounds__(256) void scan1_kernel(const int* __restrict__ cnt,
                                                    int* __restrict__ excl,
                                                    int* __restrict__ partial, int n) {
    __shared__ int sd[256];
    int tid = threadIdx.x;
    int i = blockIdx.x * 256 + tid;
    int v = (i < n) ? cnt[i] : 0;
    sd[tid] = v;
    __syncthreads();
    #pragma unroll
    for (int off = 1; off < 256; off <<= 1) {
        int t = (tid >= off) ? sd[tid - off] : 0;
        __syncthreads();
        sd[tid] += t;
        __syncthreads();
    }
    if (i < n) excl[i] = sd[tid] - v;
    if (tid == 255) partial[blockIdx.x] = sd[255];
}

__global__ __launch_bounds__(256) void scan2_kernel(int* __restrict__ partial, int nb) {
    __shared__ int sd[256];
    int tid = threadIdx.x;
    int v = (tid < nb) ? partial[tid] : 0;
    sd[tid] = v;
    __syncthreads();
    #pragma unroll
    for (int off = 1; off < 256; off <<= 1) {
        int t = (tid >= off) ? sd[tid - off] : 0;
        __syncthreads();
        sd[tid] += t;
        __syncthreads();
    }
    if (tid < nb) partial[tid] = sd[tid] - v;   // exclusive
}

__global__ __launch_bounds__(256) void scan3_kernel(const int* __restrict__ excl,
                                                    const int* __restrict__ partial,
                                                    int* __restrict__ row_ptr,
                                                    int* __restrict__ row_tmp, int n) {
    int i = blockIdx.x * 256 + threadIdx.x;
    if (i < n) {
        int v = excl[i] + partial[blockIdx.x];
        row_ptr[i] = v;
        row_tmp[i] = v;
    }
    if (i == 0) row_ptr[n] = N_EDGES;
}

__global__ void scatter_kernel(const int* __restrict__ src, const int* __restrict__ dst,
                               int* __restrict__ row_tmp, int* __restrict__ sorted_src,
                               int* __restrict__ sorted_dst, int E) {
    int i = blockIdx.x * blockDim.x + threadIdx.x;
    if (i < E) {
        int d = dst[i];
        int p = atomicAdd(&row_tmp[d], 1);
        sorted_src[p] = src[i];
        sorted_dst[p] = d;
    }
}

// ---------------- W prep: transpose + bf16 hi/lo split, both layers ---------
__global__ void prep_w(const float* __restrict__ W1, const float* __restrict__ W2,
                       ushort* __restrict__ Wt1_hi, ushort* __restrict__ Wt1_lo,
                       ushort* __restrict__ Wt2_hi, ushort* __restrict__ Wt2_lo) {
    int n = threadIdx.x, k = blockIdx.x & 255;
    const float* W = (blockIdx.x < 256) ? W1 : W2;
    ushort* Wh = (blockIdx.x < 256) ? Wt1_hi : Wt2_hi;
    ushort* Wl = (blockIdx.x < 256) ? Wt1_lo : Wt2_lo;
    float v = W[k * 256 + n];
    ushort hb = f2bf(v);
    Wh[n * 256 + k] = hb;
    Wl[n * 256 + k] = f2bf(v - bfu2f(hb));
}

// ------- GEMM + fused attention logits, col-split -------
// Block: 64 rows x 128 cols; blockIdx.y=0 -> cols 0..127 (heads 0,1),
// blockIdx.y=1 -> cols 128..255 (heads 2,3). bf16x3 split MFMA.
__global__ __launch_bounds__(256) void gemm_att_kernel(const float* __restrict__ A,
                                                       const ushort* __restrict__ Wt_hi,
                                                       const ushort* __restrict__ Wt_lo,
                                                       const float* __restrict__ att_s,
                                                       const float* __restrict__ att_d,
                                                       ushort* __restrict__ H,
                                                       float* __restrict__ a_src,
                                                       float* __restrict__ a_dst, int M) {
    const int ROWP = 40;
    __shared__ ushort hi_s[128 * ROWP];   // 10 KB
    __shared__ ushort lo_s[128 * ROWP];   // 10 KB
    const int tid = threadIdx.x;
    const int wave = tid >> 6, lane = tid & 63;
    const int quad = lane >> 4, l16 = lane & 15;
    const int brow = blockIdx.x * 64;
    const int coff = blockIdx.y * 128;    // column offset (also Wt row offset)
    const int mrow = brow + wave * 16 + l16;
    const int mload = (mrow < M) ? mrow : (M - 1);

    floatx4 acc[8];
    #pragma unroll
    for (int t = 0; t < 8; t++) acc[t] = (floatx4){0.f, 0.f, 0.f, 0.f};

    for (int k0 = 0; k0 < 256; k0 += 32) {
        __syncthreads();
        {   // stage 128 cols x 32 k: threads 0-127 stage hi, 128-255 stage lo
            int t = tid & 127;
            const ushort* g = ((tid < 128) ? Wt_hi : Wt_lo) + (size_t)(coff + t) * 256 + k0;
            ushort* d = ((tid < 128) ? hi_s : lo_s) + t * ROWP;
            #pragma unroll
            for (int i = 0; i < 4; i++)
                *reinterpret_cast<short8*>(d + i * 8) =
                    *reinterpret_cast<const short8*>(g + i * 8);
        }
        __syncthreads();
        const float* ap = A + (size_t)mload * 256 + k0 + quad * 8;
        float4 a0 = *reinterpret_cast<const float4*>(ap);
        float4 a1 = *reinterpret_cast<const float4*>(ap + 4);
        float av[8] = {a0.x, a0.y, a0.z, a0.w, a1.x, a1.y, a1.z, a1.w};
        short8 a_hi, a_lo;
        #pragma unroll
        for (int j = 0; j < 8; j++) {
            ushort hb = f2bf(av[j]);
            a_hi[j] = (short)hb;
            a_lo[j] = (short)f2bf(av[j] - bfu2f(hb));
        }
        #pragma unroll
        for (int t = 0; t < 8; t++) {
            int roff = (t * 16 + l16) * ROWP + quad * 8;
            short8 b_hi = *reinterpret_cast<const short8*>(&hi_s[roff]);
            short8 b_lo = *reinterpret_cast<const short8*>(&lo_s[roff]);
            acc[t] = __builtin_amdgcn_mfma_f32_16x16x32_bf16(a_hi, b_hi, acc[t], 0, 0, 0);
            acc[t] = __builtin_amdgcn_mfma_f32_16x16x32_bf16(a_hi, b_lo, acc[t], 0, 0, 0);
            acc[t] = __builtin_amdgcn_mfma_f32_16x16x32_bf16(a_lo, b_hi, acc[t], 0, 0, 0);
        }
    }
    // fused attention-logit partials: tiles 0-3 -> head coff/64, 4-7 -> +1
    const int hb = blockIdx.y * 2;
    float ps[2][4] = {}, pd[2][4] = {};
    #pragma unroll
    for (int t = 0; t < 8; t++) {
        int hh = t >> 2;
        float as_v = att_s[coff + t * 16 + l16];
        float ad_v = att_d[coff + t * 16 + l16];
        #pragma unroll
        for (int r = 0; r < 4; r++) {
            ps[hh][r] += acc[t][r] * as_v;
            pd[hh][r] += acc[t][r] * ad_v;
        }
    }
    #pragma unroll
    for (int off = 1; off < 16; off <<= 1) {
        #pragma unroll
        for (int hh = 0; hh < 2; hh++)
            #pragma unroll
            for (int r = 0; r < 4; r++) {
                ps[hh][r] += __shfl_xor(ps[hh][r], off, 64);
                pd[hh][r] += __shfl_xor(pd[hh][r], off, 64);
            }
    }
    if (l16 == 0) {
        #pragma unroll
        for (int r = 0; r < 4; r++) {
            int m = brow + wave * 16 + quad * 4 + r;
            if (m < M) {
                #pragma unroll
                for (int hh = 0; hh < 2; hh++) {
                    a_src[m * 4 + hb + hh] = ps[hh][r];
                    a_dst[m * 4 + hb + hh] = pd[hh][r];
                }
            }
        }
    }
    // store bf16 H, interleaved (c*4 + h)
    #pragma unroll
    for (int t = 0; t < 8; t++) {
        int col = coff + t * 16 + l16;
        int c = col & 63, hh = col >> 6;
        #pragma unroll
        for (int r = 0; r < 4; r++) {
            int m = brow + wave * 16 + quad * 4 + r;
            if (m < M) H[(size_t)m * 256 + c * 4 + hh] = f2bf(acc[t][r]);
        }
    }
}

// ---------------- edge weights: w = exp(lrelu(a_src[s]+a_dst[d])) -----------
// No max-subtraction: logits bounded (|e| ~ O(10)), f32 exp safe; alpha = w/sum(w)
// is mathematically identical to the max-subtracted form.
__global__ __launch_bounds__(256) void ew_kernel(const float* __restrict__ a_src,
                                                 const float* __restrict__ a_dst,
                                                 const int* __restrict__ sorted_src,
                                                 const int* __restrict__ sorted_dst,
                                                 float* __restrict__ ew, int E) {
    int j = blockIdx.x * 256 + threadIdx.x;
    if (j >= E) return;
    int s = sorted_src[j], d = sorted_dst[j];
    float4 as_ = *reinterpret_cast<const float4*>(a_src + (size_t)s * 4);
    float4 ad_ = *reinterpret_cast<const float4*>(a_dst + (size_t)d * 4);
    float4 w;
    w.x = __expf(lrelu(as_.x + ad_.x));
    w.y = __expf(lrelu(as_.y + ad_.y));
    w.z = __expf(lrelu(as_.z + ad_.z));
    w.w = __expf(lrelu(as_.w + ad_.w));
    *reinterpret_cast<float4*>(ew + (size_t)j * 4) = w;
}

// ---------------- weighted gather, one wave per node ------------------------
// Two 32-lane halves process alternating edges; lane covers channels
// {2*hl, 2*hl+1} x 4 heads via one uint4 load. Weights precomputed (ew).
__global__ __launch_bounds__(256) void agg_kernel(const ushort* __restrict__ H,
                                                  const float* __restrict__ a_src,
                                                  const float* __restrict__ a_dst,
                                                  const int* __restrict__ row_ptr,
                                                  const int* __restrict__ sorted_src,
                                                  const float* __restrict__ ew,
                                                  const float* __restrict__ bias,
                                                  float* __restrict__ out, int N) {
    int wave = threadIdx.x >> 6, lane = threadIdx.x & 63;
    int half = lane >> 5, hl = lane & 31;
    int i = blockIdx.x * 4 + wave;
    if (i >= N) return;
    float4 asv = *reinterpret_cast<const float4*>(a_src + (size_t)i * 4);
    float4 adv = *reinterpret_cast<const float4*>(a_dst + (size_t)i * 4);
    float ws0 = __expf(lrelu(asv.x + adv.x)), ws1 = __expf(lrelu(asv.y + adv.y));
    float ws2 = __expf(lrelu(asv.z + adv.z)), ws3 = __expf(lrelu(asv.w + adv.w));
    int start = row_ptr[i], end = row_ptr[i + 1];

    // accumulators: channels c=2*hl (a*) and c=2*hl+1 (b*), per head
    float a0 = 0.f, a1 = 0.f, a2 = 0.f, a3 = 0.f;
    float b0 = 0.f, b1 = 0.f, b2 = 0.f, b3 = 0.f;
    float dp0 = 0.f, dp1 = 0.f, dp2 = 0.f, dp3 = 0.f;

    for (int j = start + half; j < end; j += 2) {
        int sj = sorted_src[j];                                        // broadcast
        float4 w = *reinterpret_cast<const float4*>(ew + (size_t)j * 4);  // broadcast
        uint4 hv = *reinterpret_cast<const uint4*>(H + (size_t)sj * 256 + hl * 8);
        a0 += w.x * bflo(hv.x); a1 += w.y * bfhi(hv.x);
        a2 += w.z * bflo(hv.y); a3 += w.w * bfhi(hv.y);
        b0 += w.x * bflo(hv.z); b1 += w.y * bfhi(hv.z);
        b2 += w.z * bflo(hv.w); b3 += w.w * bfhi(hv.w);
        dp0 += w.x; dp1 += w.y; dp2 += w.z; dp3 += w.w;
    }
    // merge the two halves (disjoint edges, same channels)
    a0 += __shfl_xor(a0, 32, 64); a1 += __shfl_xor(a1, 32, 64);
    a2 += __shfl_xor(a2, 32, 64); a3 += __shfl_xor(a3, 32, 64);
    b0 += __shfl_xor(b0, 32, 64); b1 += __shfl_xor(b1, 32, 64);
    b2 += __shfl_xor(b2, 32, 64); b3 += __shfl_xor(b3, 32, 64);
    dp0 += __shfl_xor(dp0, 32, 64); dp1 += __shfl_xor(dp1, 32, 64);
    dp2 += __shfl_xor(dp2, 32, 64); dp3 += __shfl_xor(dp3, 32, 64);
    // self loop
    {
        uint4 hv = *reinterpret_cast<const uint4*>(H + (size_t)i * 256 + hl * 8);
        a0 += ws0 * bflo(hv.x); a1 += ws1 * bfhi(hv.x);
        a2 += ws2 * bflo(hv.y); a3 += ws3 * bfhi(hv.y);
        b0 += ws0 * bflo(hv.z); b1 += ws1 * bfhi(hv.z);
        b2 += ws2 * bflo(hv.w); b3 += ws3 * bfhi(hv.w);
    }
    float r0 = 1.f / (dp0 + ws0 + 1e-16f), r1 = 1.f / (dp1 + ws1 + 1e-16f);
    float r2 = 1.f / (dp2 + ws2 + 1e-16f), r3 = 1.f / (dp3 + ws3 + 1e-16f);
    // epilogue: half0 writes heads 0,1; half1 writes heads 2,3
    float* op = out + (size_t)i * 256 + hl * 2;
    float va = (half == 0) ? a0 : a2, vb = (half == 0) ? b0 : b2;
    float ra = (half == 0) ? r0 : r2;
    float va2 = (half == 0) ? a1 : a3, vb2 = (half == 0) ? b1 : b3;
    float ra2 = (half == 0) ? r1 : r3;
    int hofs = half * 128;
    float2 o;
    float v;
    v = va * ra + bias[hofs + 2 * hl];      o.x = (v > 0.f) ? v : expm1f(v);
    v = vb * ra + bias[hofs + 2 * hl + 1];  o.y = (v > 0.f) ? v : expm1f(v);
    *reinterpret_cast<float2*>(op + hofs) = o;
    v = va2 * ra2 + bias[hofs + 64 + 2 * hl];     o.x = (v > 0.f) ? v : expm1f(v);
    v = vb2 * ra2 + bias[hofs + 64 + 2 * hl + 1]; o.y = (v > 0.f) ? v : expm1f(v);
    *reinterpret_cast<float2*>(op + hofs + 64) = o;
}

extern "C" void kernel_launch(void* const* d_in, const int* in_sizes, int n_in,
                              void* d_out, int out_size, void* d_ws, size_t ws_size,
                              hipStream_t stream) {
    const float* x      = (const float*)d_in[0];
    const int*   eidx   = (const int*)d_in[1];
    const float* W1     = (const float*)d_in[2];
    const float* att_s1 = (const float*)d_in[3];
    const float* att_d1 = (const float*)d_in[4];
    const float* b1     = (const float*)d_in[5];
    const float* W2     = (const float*)d_in[6];
    const float* att_s2 = (const float*)d_in[7];
    const float* att_d2 = (const float*)d_in[8];
    const float* b2     = (const float*)d_in[9];
    float* out = (float*)d_out;

    const int N = N_NODES, E = N_EDGES;
    char* ws = (char*)d_ws;
    size_t off = 0;
    auto alloc = [&](size_t bytes) -> void* {
        void* p = ws + off;
        off += (bytes + 255) & ~(size_t)255;
        return p;
    };
    // total ws ~ 48 MB (proven-good envelope: 57 MB)
    ushort* h       = (ushort*)alloc((size_t)N * 256 * sizeof(ushort));  // 25.6 MB
    float*  ew      = (float*) alloc((size_t)E * 4 * sizeof(float));     // 12.8 MB
    float*  a_src   = (float*) alloc((size_t)N * 4 * sizeof(float));
    float*  a_dst   = (float*) alloc((size_t)N * 4 * sizeof(float));
    int*    cnt     = (int*)   alloc((size_t)N * sizeof(int));
    int*    row_ptr = (int*)   alloc((size_t)(N + 1) * sizeof(int));
    int*    row_tmp = (int*)   alloc((size_t)N * sizeof(int));
    int*    sorted  = (int*)   alloc((size_t)E * sizeof(int));
    int*    sortedd = (int*)   alloc((size_t)E * sizeof(int));
    int*    excl    = (int*)   alloc((size_t)N * sizeof(int));
    int*    partial = (int*)   alloc(256 * sizeof(int));
    ushort* Wt1_hi  = (ushort*)alloc(256 * 256 * sizeof(ushort));
    ushort* Wt1_lo  = (ushort*)alloc(256 * 256 * sizeof(ushort));
    ushort* Wt2_hi  = (ushort*)alloc(256 * 256 * sizeof(ushort));
    ushort* Wt2_lo  = (ushort*)alloc(256 * 256 * sizeof(ushort));
    float*  x2      = out;   // layer-1 f32 activations live in d_out, overwritten by layer 2
    (void)ws_size; (void)in_sizes; (void)n_in; (void)out_size;

    const int* e_src = eidx;
    const int* e_dst = eidx + E;
    const int nsb = (N + 255) / 256;   // 196 scan blocks
    const int neb = (E + 255) / 256;

    prep_w<<<512, 256, 0, stream>>>(W1, W2, Wt1_hi, Wt1_lo, Wt2_hi, Wt2_lo);
    hipMemsetAsync(cnt, 0, N * sizeof(int), stream);
    deg_kernel<<<neb, 256, 0, stream>>>(e_dst, cnt, E);
    scan1_kernel<<<nsb, 256, 0, stream>>>(cnt, excl, partial, N);
    scan2_kernel<<<1, 256, 0, stream>>>(partial, nsb);
    scan3_kernel<<<nsb, 256, 0, stream>>>(excl, partial, row_ptr, row_tmp, N);
    scatter_kernel<<<neb, 256, 0, stream>>>(e_src, e_dst, row_tmp, sorted, sortedd, E);

    dim3 ggrid((N + 63) / 64, 2);  // 782 x 2
    int nblk = (N + 3) / 4;        // 12500
    // layer 1
    gemm_att_kernel<<<ggrid, 256, 0, stream>>>(x, Wt1_hi, Wt1_lo, att_s1, att_d1,
                                               h, a_src, a_dst, N);
    ew_kernel<<<neb, 256, 0, stream>>>(a_src, a_dst, sorted, sortedd, ew, E);
    agg_kernel<<<nblk, 256, 0, stream>>>(h, a_src, a_dst, row_ptr, sorted, ew, b1, x2, N);
    // layer 2
    gemm_att_kernel<<<ggrid, 256, 0, stream>>>(x2, Wt2_hi, Wt2_lo, att_s2, att_d2,
                                               h, a_src, a_dst, N);
    ew_kernel<<<neb, 256, 0, stream>>>(a_src, a_dst, sorted, sortedd, ew, E);
    agg_kernel<<<nblk, 256, 0, stream>>>(h, a_src, a_dst, row_ptr, sorted, ew, b2, out, N);
}